// Round 5
// baseline (122.400 us; speedup 1.0000x reference)
//
#include <hip/hip_runtime.h>

#define DIM 128          // x is (2,4,128,128,128) -> NC=8 volumes of 128^3
#define NCV 8

using f32x4 = __attribute__((ext_vector_type(4))) float;
using f32x2 = __attribute__((ext_vector_type(2))) float;

// Fused 2-level 3D Haar DWT, fp32 in / fp32 out.
// Per block: x-tile 8(D) x 8(H) x 128(W, full row) at (nc, td*8, th*8, 0).
// Phase 1: 256 threads; each owns a 2(d) x 2(h) x 8(w) input block
//          -> 4 w-adjacent level-1 sites; 7 high bands stored as one
//          nontemporal f32x4 each (16 lanes -> 256 B coalesced segments);
//          LLL -> LDS (fp32).
// Phase 2: 128 threads; level-2 butterfly from LDS -> LL2 + 7 high bands,
//          32-lane x 4 B = 128 B coalesced row segments.
__global__ __launch_bounds__(256)
void haar3d_fused(const float* __restrict__ x,
                  const float* __restrict__ h0,
                  const float* __restrict__ h1,
                  float* __restrict__ ll2,   // (NC, 32,32,32)
                  float* __restrict__ hi1,   // (NC, 7, 64,64,64)
                  float* __restrict__ hi2)   // (NC, 7, 32,32,32)
{
    __shared__ f32x2 lds[4 * 4 * 32];   // [sd][sh][w-site-pair] LLL values, 4 KiB

    const int th = blockIdx.x;        // 0..15
    const int td = blockIdx.y;        // 0..15
    const int nc = blockIdx.z;        // 0..7

    const int tid = threadIdx.x;
    const int swq = tid & 15;         // 0..15  (w-site quad: sites 4q..4q+3)
    const int sh  = (tid >> 4) & 3;   // 0..3
    const int sd  = tid >> 6;         // 0..3

    const float g00 = h0[0], g01 = h0[1];
    const float g10 = h1[0], g11 = h1[1];

    // ---------------- phase 1: level 1 ----------------
    const int gd = td * 8 + 2 * sd;
    const int gh = th * 8 + 2 * sh;
    const int gw = 8 * swq;           // 32B-aligned

    const float* base = x + ((((long)nc * DIM + gd) * DIM + gh) * DIM + gw);

    // q[i][j][p]: d-offset i, h-offset j, p=0 -> w 0..3, p=1 -> w 4..7
    f32x4 q[2][2][2];
#pragma unroll
    for (int i = 0; i < 2; ++i)
#pragma unroll
        for (int j = 0; j < 2; ++j) {
            const f32x4* r = reinterpret_cast<const f32x4*>(base + i * DIM * DIM + j * DIM);
            q[i][j][0] = __builtin_nontemporal_load(r);
            q[i][j][1] = __builtin_nontemporal_load(r + 1);
        }

    // W stage: 4 sites s=0..3 from element pairs (0,1),(2,3) of each f32x4
    float Lw[2][2][4], Hw[2][2][4];   // [i][j][s]
#pragma unroll
    for (int i = 0; i < 2; ++i)
#pragma unroll
        for (int j = 0; j < 2; ++j) {
            const f32x4 A = q[i][j][0];
            const f32x4 B = q[i][j][1];
            Lw[i][j][0] = g00 * A[0] + g01 * A[1];  Hw[i][j][0] = g10 * A[0] + g11 * A[1];
            Lw[i][j][1] = g00 * A[2] + g01 * A[3];  Hw[i][j][1] = g10 * A[2] + g11 * A[3];
            Lw[i][j][2] = g00 * B[0] + g01 * B[1];  Hw[i][j][2] = g10 * B[0] + g11 * B[1];
            Lw[i][j][3] = g00 * B[2] + g01 * B[3];  Hw[i][j][3] = g10 * B[2] + g11 * B[3];
        }

    // H stage; names [w-band][h-band]
    float LL[2][4], LH[2][4], HL[2][4], HH[2][4];   // [i][s]
#pragma unroll
    for (int i = 0; i < 2; ++i)
#pragma unroll
        for (int s = 0; s < 4; ++s) {
            LL[i][s] = g00 * Lw[i][0][s] + g01 * Lw[i][1][s];
            LH[i][s] = g10 * Lw[i][0][s] + g11 * Lw[i][1][s];
            HL[i][s] = g00 * Hw[i][0][s] + g01 * Hw[i][1][s];
            HH[i][s] = g10 * Hw[i][0][s] + g11 * Hw[i][1][s];
        }

    // D stage; band value vectors over 4 sites; names [w-band][h-band][d-band]
    f32x4 vLLL, vLLH, vLHL, vLHH, vHLL, vHLH, vHHL, vHHH;
#pragma unroll
    for (int s = 0; s < 4; ++s) {
        vLLL[s] = g00 * LL[0][s] + g01 * LL[1][s];
        vLLH[s] = g10 * LL[0][s] + g11 * LL[1][s];
        vLHL[s] = g00 * LH[0][s] + g01 * LH[1][s];
        vLHH[s] = g10 * LH[0][s] + g11 * LH[1][s];
        vHLL[s] = g00 * HL[0][s] + g01 * HL[1][s];
        vHLH[s] = g10 * HL[0][s] + g11 * HL[1][s];
        vHHL[s] = g00 * HH[0][s] + g01 * HH[1][s];
        vHHH[s] = g10 * HH[0][s] + g11 * HH[1][s];
    }

    // level-1 site coords
    const int d1  = td * 4 + sd;
    const int h1c = th * 4 + sh;
    const int w1  = 4 * swq;          // 16B-aligned f32x4 store

    // band order: b = bw*4 + bh*2 + bd; highs are b=1..7 -> plane b-1
    {
        const long S1 = 64L * 64 * 64;
        float* hb = hi1 + (long)nc * 7 * S1 + (((long)d1 * 64 + h1c) * 64 + w1);
        __builtin_nontemporal_store(vLLH, reinterpret_cast<f32x4*>(hb + 0 * S1));
        __builtin_nontemporal_store(vLHL, reinterpret_cast<f32x4*>(hb + 1 * S1));
        __builtin_nontemporal_store(vLHH, reinterpret_cast<f32x4*>(hb + 2 * S1));
        __builtin_nontemporal_store(vHLL, reinterpret_cast<f32x4*>(hb + 3 * S1));
        __builtin_nontemporal_store(vHLH, reinterpret_cast<f32x4*>(hb + 4 * S1));
        __builtin_nontemporal_store(vHHL, reinterpret_cast<f32x4*>(hb + 5 * S1));
        __builtin_nontemporal_store(vHHH, reinterpret_cast<f32x4*>(hb + 6 * S1));
    }

    // LLL -> LDS: sites 4*swq..4*swq+3 -> f32x2 pair indices 2*swq, 2*swq+1
    {
        f32x2* dst = &lds[((sd * 4 + sh) * 32) + 2 * swq];
        f32x2 lo01; lo01[0] = vLLL[0]; lo01[1] = vLLL[1];
        f32x2 lo23; lo23[0] = vLLL[2]; lo23[1] = vLLL[3];
        dst[0] = lo01;
        dst[1] = lo23;
    }

    __syncthreads();

    // ---------------- phase 2: level 2 from LDS ----------------
    if (tid < 128) {
        const int zw = tid & 31;         // 0..31 (level-2 w site)
        const int zh = (tid >> 5) & 1;   // 0..1
        const int zd = tid >> 6;         // 0..1

        float Lw2[2][2], Hw2[2][2];      // [i][j]
#pragma unroll
        for (int i = 0; i < 2; ++i)
#pragma unroll
            for (int j = 0; j < 2; ++j) {
                const f32x2 p = lds[((2 * zd + i) * 4 + (2 * zh + j)) * 32 + zw];
                Lw2[i][j] = g00 * p[0] + g01 * p[1];
                Hw2[i][j] = g10 * p[0] + g11 * p[1];
            }

        float LL2v[2], LH2[2], HL2[2], HH2[2];   // [i]
#pragma unroll
        for (int i = 0; i < 2; ++i) {
            LL2v[i] = g00 * Lw2[i][0] + g01 * Lw2[i][1];
            LH2[i]  = g10 * Lw2[i][0] + g11 * Lw2[i][1];
            HL2[i]  = g00 * Hw2[i][0] + g01 * Hw2[i][1];
            HH2[i]  = g10 * Hw2[i][0] + g11 * Hw2[i][1];
        }

        const float oLLL = g00 * LL2v[0] + g01 * LL2v[1];
        const float oLLH = g10 * LL2v[0] + g11 * LL2v[1];
        const float oLHL = g00 * LH2[0]  + g01 * LH2[1];
        const float oLHH = g10 * LH2[0]  + g11 * LH2[1];
        const float oHLL = g00 * HL2[0]  + g01 * HL2[1];
        const float oHLH = g10 * HL2[0]  + g11 * HL2[1];
        const float oHHL = g00 * HH2[0]  + g01 * HH2[1];
        const float oHHH = g10 * HH2[0]  + g11 * HH2[1];

        const int d2 = td * 2 + zd;
        const int h2 = th * 2 + zh;
        const int w2 = zw;

        __builtin_nontemporal_store(
            oLLL, &ll2[(((long)nc * 32 + d2) * 32 + h2) * 32 + w2]);

        const long S2 = 32L * 32 * 32;
        float* hb2 = hi2 + (long)nc * 7 * S2 + (((long)d2 * 32 + h2) * 32 + w2);
        __builtin_nontemporal_store(oLLH, hb2 + 0 * S2);
        __builtin_nontemporal_store(oLHL, hb2 + 1 * S2);
        __builtin_nontemporal_store(oLHH, hb2 + 2 * S2);
        __builtin_nontemporal_store(oHLL, hb2 + 3 * S2);
        __builtin_nontemporal_store(oHLH, hb2 + 4 * S2);
        __builtin_nontemporal_store(oHHL, hb2 + 5 * S2);
        __builtin_nontemporal_store(oHHH, hb2 + 6 * S2);
    }
}

extern "C" void kernel_launch(void* const* d_in, const int* in_sizes, int n_in,
                              void* d_out, int out_size, void* d_ws, size_t ws_size,
                              hipStream_t stream) {
    const float* x  = (const float*)d_in[0];
    const float* h0 = (const float*)d_in[1];
    const float* h1 = (const float*)d_in[2];
    float* out = (float*)d_out;

    const long LL2_SZ = (long)NCV * 32 * 32 * 32;        //   262,144
    const long H1_SZ  = (long)NCV * 7 * 64 * 64 * 64;    // 14,680,064
    float* ll2 = out;
    float* hi1 = out + LL2_SZ;
    float* hi2 = out + LL2_SZ + H1_SZ;

    // grid: x = th (H/8 = 16), y = td (D/8 = 16), z = nc (8)
    dim3 grid(16, 16, NCV);
    haar3d_fused<<<grid, 256, 0, stream>>>(x, h0, h1, ll2, hi1, hi2);
}

// Round 6
// 109.378 us; speedup vs baseline: 1.1191x; 1.1191x over previous
//
#include <hip/hip_runtime.h>

#define DIM 128          // x is (2,4,128,128,128) -> NC=8 volumes of 128^3
#define NCV 8

using f32x4 = __attribute__((ext_vector_type(4))) float;
using f32x2 = __attribute__((ext_vector_type(2))) float;

// Fused 2-level 3D Haar DWT, fp32 in / fp32 out.
// Per block: x-tile 8(D) x 8(H) x 128(W, full row) at (nc, td*8, th*8, 0).
// Loads: PLAIN f32x4 (x is L3-resident from the harness restore; NT loads
//        bypassed L3 and cost +8 us in R5).
// Stores: nontemporal (streamed-once outputs, keep L2/L3 clean for x).
// Phase 1: 256 threads; each owns a 2(d) x 2(h) x 8(w) input block
//          -> 4 w-adjacent level-1 sites; 7 high bands stored as one
//          NT f32x4 each (16 lanes -> 256 B coalesced segments);
//          LLL -> LDS (fp32).
// Phase 2: 128 threads; level-2 butterfly from LDS -> LL2 + 7 high bands,
//          32-lane x 4 B = 128 B coalesced row segments.
__global__ __launch_bounds__(256)
void haar3d_fused(const float* __restrict__ x,
                  const float* __restrict__ h0,
                  const float* __restrict__ h1,
                  float* __restrict__ ll2,   // (NC, 32,32,32)
                  float* __restrict__ hi1,   // (NC, 7, 64,64,64)
                  float* __restrict__ hi2)   // (NC, 7, 32,32,32)
{
    __shared__ f32x2 lds[4 * 4 * 32];   // [sd][sh][w-site-pair] LLL values, 4 KiB

    const int th = blockIdx.x;        // 0..15
    const int td = blockIdx.y;        // 0..15
    const int nc = blockIdx.z;        // 0..7

    const int tid = threadIdx.x;
    const int swq = tid & 15;         // 0..15  (w-site quad: sites 4q..4q+3)
    const int sh  = (tid >> 4) & 3;   // 0..3
    const int sd  = tid >> 6;         // 0..3

    const float g00 = h0[0], g01 = h0[1];
    const float g10 = h1[0], g11 = h1[1];

    // ---------------- phase 1: level 1 ----------------
    const int gd = td * 8 + 2 * sd;
    const int gh = th * 8 + 2 * sh;
    const int gw = 8 * swq;           // 32B-aligned

    const float* base = x + ((((long)nc * DIM + gd) * DIM + gh) * DIM + gw);

    // q[i][j][p]: d-offset i, h-offset j, p=0 -> w 0..3, p=1 -> w 4..7
    f32x4 q[2][2][2];
#pragma unroll
    for (int i = 0; i < 2; ++i)
#pragma unroll
        for (int j = 0; j < 2; ++j) {
            const f32x4* r = reinterpret_cast<const f32x4*>(base + i * DIM * DIM + j * DIM);
            q[i][j][0] = r[0];
            q[i][j][1] = r[1];
        }

    // W stage: 4 sites s=0..3 from element pairs (0,1),(2,3) of each f32x4
    float Lw[2][2][4], Hw[2][2][4];   // [i][j][s]
#pragma unroll
    for (int i = 0; i < 2; ++i)
#pragma unroll
        for (int j = 0; j < 2; ++j) {
            const f32x4 A = q[i][j][0];
            const f32x4 B = q[i][j][1];
            Lw[i][j][0] = g00 * A[0] + g01 * A[1];  Hw[i][j][0] = g10 * A[0] + g11 * A[1];
            Lw[i][j][1] = g00 * A[2] + g01 * A[3];  Hw[i][j][1] = g10 * A[2] + g11 * A[3];
            Lw[i][j][2] = g00 * B[0] + g01 * B[1];  Hw[i][j][2] = g10 * B[0] + g11 * B[1];
            Lw[i][j][3] = g00 * B[2] + g01 * B[3];  Hw[i][j][3] = g10 * B[2] + g11 * B[3];
        }

    // H stage; names [w-band][h-band]
    float LL[2][4], LH[2][4], HL[2][4], HH[2][4];   // [i][s]
#pragma unroll
    for (int i = 0; i < 2; ++i)
#pragma unroll
        for (int s = 0; s < 4; ++s) {
            LL[i][s] = g00 * Lw[i][0][s] + g01 * Lw[i][1][s];
            LH[i][s] = g10 * Lw[i][0][s] + g11 * Lw[i][1][s];
            HL[i][s] = g00 * Hw[i][0][s] + g01 * Hw[i][1][s];
            HH[i][s] = g10 * Hw[i][0][s] + g11 * Hw[i][1][s];
        }

    // D stage; band value vectors over 4 sites; names [w-band][h-band][d-band]
    f32x4 vLLL, vLLH, vLHL, vLHH, vHLL, vHLH, vHHL, vHHH;
#pragma unroll
    for (int s = 0; s < 4; ++s) {
        vLLL[s] = g00 * LL[0][s] + g01 * LL[1][s];
        vLLH[s] = g10 * LL[0][s] + g11 * LL[1][s];
        vLHL[s] = g00 * LH[0][s] + g01 * LH[1][s];
        vLHH[s] = g10 * LH[0][s] + g11 * LH[1][s];
        vHLL[s] = g00 * HL[0][s] + g01 * HL[1][s];
        vHLH[s] = g10 * HL[0][s] + g11 * HL[1][s];
        vHHL[s] = g00 * HH[0][s] + g01 * HH[1][s];
        vHHH[s] = g10 * HH[0][s] + g11 * HH[1][s];
    }

    // level-1 site coords
    const int d1  = td * 4 + sd;
    const int h1c = th * 4 + sh;
    const int w1  = 4 * swq;          // 16B-aligned f32x4 store

    // band order: b = bw*4 + bh*2 + bd; highs are b=1..7 -> plane b-1
    {
        const long S1 = 64L * 64 * 64;
        float* hb = hi1 + (long)nc * 7 * S1 + (((long)d1 * 64 + h1c) * 64 + w1);
        __builtin_nontemporal_store(vLLH, reinterpret_cast<f32x4*>(hb + 0 * S1));
        __builtin_nontemporal_store(vLHL, reinterpret_cast<f32x4*>(hb + 1 * S1));
        __builtin_nontemporal_store(vLHH, reinterpret_cast<f32x4*>(hb + 2 * S1));
        __builtin_nontemporal_store(vHLL, reinterpret_cast<f32x4*>(hb + 3 * S1));
        __builtin_nontemporal_store(vHLH, reinterpret_cast<f32x4*>(hb + 4 * S1));
        __builtin_nontemporal_store(vHHL, reinterpret_cast<f32x4*>(hb + 5 * S1));
        __builtin_nontemporal_store(vHHH, reinterpret_cast<f32x4*>(hb + 6 * S1));
    }

    // LLL -> LDS: sites 4*swq..4*swq+3 -> f32x2 pair indices 2*swq, 2*swq+1
    {
        f32x2* dst = &lds[((sd * 4 + sh) * 32) + 2 * swq];
        f32x2 lo01; lo01[0] = vLLL[0]; lo01[1] = vLLL[1];
        f32x2 lo23; lo23[0] = vLLL[2]; lo23[1] = vLLL[3];
        dst[0] = lo01;
        dst[1] = lo23;
    }

    __syncthreads();

    // ---------------- phase 2: level 2 from LDS ----------------
    if (tid < 128) {
        const int zw = tid & 31;         // 0..31 (level-2 w site)
        const int zh = (tid >> 5) & 1;   // 0..1
        const int zd = tid >> 6;         // 0..1

        float Lw2[2][2], Hw2[2][2];      // [i][j]
#pragma unroll
        for (int i = 0; i < 2; ++i)
#pragma unroll
            for (int j = 0; j < 2; ++j) {
                const f32x2 p = lds[((2 * zd + i) * 4 + (2 * zh + j)) * 32 + zw];
                Lw2[i][j] = g00 * p[0] + g01 * p[1];
                Hw2[i][j] = g10 * p[0] + g11 * p[1];
            }

        float LL2v[2], LH2[2], HL2[2], HH2[2];   // [i]
#pragma unroll
        for (int i = 0; i < 2; ++i) {
            LL2v[i] = g00 * Lw2[i][0] + g01 * Lw2[i][1];
            LH2[i]  = g10 * Lw2[i][0] + g11 * Lw2[i][1];
            HL2[i]  = g00 * Hw2[i][0] + g01 * Hw2[i][1];
            HH2[i]  = g10 * Hw2[i][0] + g11 * Hw2[i][1];
        }

        const float oLLL = g00 * LL2v[0] + g01 * LL2v[1];
        const float oLLH = g10 * LL2v[0] + g11 * LL2v[1];
        const float oLHL = g00 * LH2[0]  + g01 * LH2[1];
        const float oLHH = g10 * LH2[0]  + g11 * LH2[1];
        const float oHLL = g00 * HL2[0]  + g01 * HL2[1];
        const float oHLH = g10 * HL2[0]  + g11 * HL2[1];
        const float oHHL = g00 * HH2[0]  + g01 * HH2[1];
        const float oHHH = g10 * HH2[0]  + g11 * HH2[1];

        const int d2 = td * 2 + zd;
        const int h2 = th * 2 + zh;
        const int w2 = zw;

        __builtin_nontemporal_store(
            oLLL, &ll2[(((long)nc * 32 + d2) * 32 + h2) * 32 + w2]);

        const long S2 = 32L * 32 * 32;
        float* hb2 = hi2 + (long)nc * 7 * S2 + (((long)d2 * 32 + h2) * 32 + w2);
        __builtin_nontemporal_store(oLLH, hb2 + 0 * S2);
        __builtin_nontemporal_store(oLHL, hb2 + 1 * S2);
        __builtin_nontemporal_store(oLHH, hb2 + 2 * S2);
        __builtin_nontemporal_store(oHLL, hb2 + 3 * S2);
        __builtin_nontemporal_store(oHLH, hb2 + 4 * S2);
        __builtin_nontemporal_store(oHHL, hb2 + 5 * S2);
        __builtin_nontemporal_store(oHHH, hb2 + 6 * S2);
    }
}

extern "C" void kernel_launch(void* const* d_in, const int* in_sizes, int n_in,
                              void* d_out, int out_size, void* d_ws, size_t ws_size,
                              hipStream_t stream) {
    const float* x  = (const float*)d_in[0];
    const float* h0 = (const float*)d_in[1];
    const float* h1 = (const float*)d_in[2];
    float* out = (float*)d_out;

    const long LL2_SZ = (long)NCV * 32 * 32 * 32;        //   262,144
    const long H1_SZ  = (long)NCV * 7 * 64 * 64 * 64;    // 14,680,064
    float* ll2 = out;
    float* hi1 = out + LL2_SZ;
    float* hi2 = out + LL2_SZ + H1_SZ;

    // grid: x = th (H/8 = 16), y = td (D/8 = 16), z = nc (8)
    dim3 grid(16, 16, NCV);
    haar3d_fused<<<grid, 256, 0, stream>>>(x, h0, h1, ll2, hi1, hi2);
}